// Round 5
// baseline (374.306 us; speedup 1.0000x reference)
//
#include <hip/hip_runtime.h>
#include <hip/hip_bf16.h>
#include <hip/hip_fp16.h>
#include <math.h>

// QAT GPT2 MLP + LoRA on MI355X — fp32 in/out.
// Round 10: three GEMM schedules all stuck at 80-88us. Revised model: per
// CU tile-pair wall 3300cyc = MFMA 1300 + LDS 1500-2200 (192KB through the
// 128B/cy port) + sync, serialized -> LDS-port + lockstep bound. Fix: A
// fragments load global->VGPR directly (16 K-contig bytes/lane; no layout
// change needed, L2-resident panel) — LDS traffic/tile halves (A ds_reads
// 32KB + A stage 16KB gone), MFMA becomes critical path. One barrier + one
// vmcnt(0) per K-tile: issue A(t+1)->regs and stageB(t+1) at tile TOP,
// drain at tile BOTTOM (~800cyc hide). No inline lgkmcnt — compiler emits
// counted waits for the b-frag ds_reads. A-regs double-buffered via
// unroll-2 (no runtime-indexed frag arrays). LDS 32KB/block.
// Fused quant_x_t1 / quant_h_t2 (MFMA LoRA-t, in-place chunked i8) kept.

typedef unsigned short u16;
typedef unsigned int u32;
typedef signed char i8;
typedef int i32x4 __attribute__((ext_vector_type(4)));
typedef _Float16 f16;
typedef f16 f16x8 __attribute__((ext_vector_type(8)));
typedef float f32x4 __attribute__((ext_vector_type(4)));

#define ASYNC16(gp, lp)                                                        \
  __builtin_amdgcn_global_load_lds(                                            \
      (__attribute__((address_space(1))) void*)(gp),                           \
      (__attribute__((address_space(3))) void*)(lp), 16, 0, 0)

#define VMCNT0 asm volatile("s_waitcnt vmcnt(0)" ::: "memory")
#define SBAR __builtin_amdgcn_s_barrier()

// quantize to int: q = clip(rint(v/s), -128, 127)
__device__ __forceinline__ int quanti(float v, float inv) {
  float q = rintf(v * inv);
  q = fminf(fmaxf(q, -128.0f), 127.0f);
  return (int)q;
}

__device__ __forceinline__ u32 pack4(float4 v, float inv) {
  return ((u32)(quanti(v.x, inv) & 255)) |
         ((u32)(quanti(v.y, inv) & 255) << 8) |
         ((u32)(quanti(v.z, inv) & 255) << 16) |
         ((u32)(quanti(v.w, inv) & 255) << 24);
}

__device__ __forceinline__ float load_scale(const u32* slot) {
  return fmaxf(__uint_as_float(*slot) * (1.0f / 127.0f), 1e-8f);
}

// exact-erf GELU via Abramowitz-Stegun 7.1.26 (|erf err| <= 1.5e-7)
__device__ __forceinline__ float gelu_erf(float v) {
  float z = fabsf(v) * 0.70710678118654752f;
  float t = __builtin_amdgcn_rcpf(fmaf(0.3275911f, z, 1.0f));
  float poly =
      t * fmaf(t,
               fmaf(t,
                    fmaf(t, fmaf(t, 1.061405429f, -1.453152027f),
                         1.421413741f),
                    -0.284496736f),
               0.254829592f);
  float e = fmaf(-poly, exp2f(-z * z * 1.4426950408889634f), 1.0f);
  return 0.5f * v * fmaf(copysignf(e, v), 1.0f, 1.0f);
}

// -------------------- absmax over fp32 tensor (float4 grid-stride) ----------
__global__ void absmax_kernel(const float* __restrict__ x, int n4,
                              u32* __restrict__ slot) {
  float m = 0.0f;
  int stride = gridDim.x * blockDim.x;
  for (int i = blockIdx.x * blockDim.x + threadIdx.x; i < n4; i += stride) {
    float4 v = ((const float4*)x)[i];
    m = fmaxf(m, fmaxf(fmaxf(fabsf(v.x), fabsf(v.y)),
                       fmaxf(fabsf(v.z), fabsf(v.w))));
  }
#pragma unroll
  for (int off = 32; off > 0; off >>= 1) m = fmaxf(m, __shfl_down(m, off));
  __shared__ float wmax[4];
  int lane = threadIdx.x & 63, wave = threadIdx.x >> 6;
  if (lane == 0) wmax[wave] = m;
  __syncthreads();
  if (threadIdx.x == 0) {
    m = fmaxf(fmaxf(wmax[0], wmax[1]), fmaxf(wmax[2], wmax[3]));
    atomicMax(slot, __float_as_uint(m));  // positive floats: bit-monotone
  }
}

// ---------------- quantize W (fp32 in, packed i8 out) -----------------------
__global__ void quant_w_kernel(const float* __restrict__ w, int n16,
                               const u32* __restrict__ slot,
                               i8* __restrict__ q) {
  float inv = 1.0f / load_scale(slot);
  int stride = gridDim.x * blockDim.x;
  for (int i = blockIdx.x * blockDim.x + threadIdx.x; i < n16; i += stride) {
    const float4* src = (const float4*)w + i * 4;
    u32 pk[4];
#pragma unroll
    for (int c = 0; c < 4; c++) pk[c] = pack4(src[c], inv);
    uint4 o = {pk[0], pk[1], pk[2], pk[3]};
    ((uint4*)q)[i] = o;
  }
}

// ---- convert A [8][ncols] fp32 -> [16][ncols] fp16, rows 8-15 zero ---------
__global__ void conv_a16_kernel(const float* __restrict__ A,
                                f16* __restrict__ Ah, int ncols) {
  int i = blockIdx.x * blockDim.x + threadIdx.x;  // one f16x8 per thread
  int base = i * 8;
  if (base >= 16 * ncols) return;
  if (base < 8 * ncols) {
    float4 v0 = ((const float4*)(A + base))[0];
    float4 v1 = ((const float4*)(A + base))[1];
    f16x8 o = {(f16)v0.x, (f16)v0.y, (f16)v0.z, (f16)v0.w,
               (f16)v1.x, (f16)v1.y, (f16)v1.z, (f16)v1.w};
    *(f16x8*)(Ah + base) = o;
  } else {
    f16x8 z = {};
    *(f16x8*)(Ah + base) = z;
  }
}

// ---- fused: quantize x (fp32 -> i8, exact) + t1 = x.Afc^T via fp16 MFMA ----
__launch_bounds__(256) __global__
    void quant_x_t1_fused(const float* __restrict__ x,   // [8192][1024]
                          const f16* __restrict__ Ah,    // [16][1024]
                          const u32* __restrict__ slot,
                          i8* __restrict__ xq,           // [8192][1024]
                          float* __restrict__ t1) {      // [8192][8], zeroed
  int tid = threadIdx.x;
  int lane = tid & 63, wave = tid >> 6;
  int quad = lane >> 4, l15 = lane & 15;
  int bx = blockIdx.x;                       // k-chunk [0,2)
  long m0 = (long)blockIdx.y * 64 + wave * 16;
  long row = m0 + l15;
  int k0 = bx * 512;
  float inv = 1.0f / load_scale(slot);

  const float* xp = x + row * 1024 + k0 + quad * 8;
  const f16* ap = Ah + l15 * 1024 + k0 + quad * 8;
  i8* op = xq + row * 1024 + k0 + quad * 8;
  f32x4 acc = {0.0f, 0.0f, 0.0f, 0.0f};
#pragma unroll
  for (int s = 0; s < 16; s++) {
    float4 v0 = ((const float4*)(xp + s * 32))[0];
    float4 v1 = ((const float4*)(xp + s * 32))[1];
    f16x8 af = {(f16)v0.x, (f16)v0.y, (f16)v0.z, (f16)v0.w,
                (f16)v1.x, (f16)v1.y, (f16)v1.z, (f16)v1.w};
    f16x8 bf = *(const f16x8*)(ap + s * 32);
    acc = __builtin_amdgcn_mfma_f32_16x16x32_f16(af, bf, acc, 0, 0, 0);
    uint2 o = {pack4(v0, inv), pack4(v1, inv)};
    *(uint2*)(op + s * 32) = o;
  }
  if (l15 < 8) {
#pragma unroll
    for (int r = 0; r < 4; r++) {
      long m = m0 + quad * 4 + r;
      atomicAdd(&t1[m * 8 + l15], acc[r]);
    }
  }
}

// ---- fused: quantize h (fp16 -> i8 in place, chunked) + t2 = h.A^T via MFMA
__launch_bounds__(256) __global__
    void quant_h_t2_fused(u16* __restrict__ h,        // [8192][4096] fp16
                          const f16* __restrict__ Ah, // [16][4096]
                          const u32* __restrict__ slot,
                          float* __restrict__ t2) {   // [8192][8], pre-zeroed
  int tid = threadIdx.x;
  int lane = tid & 63, wave = tid >> 6;
  int quad = lane >> 4, l15 = lane & 15;
  int bx = blockIdx.x;                       // k-chunk index [0,8)
  long m0 = (long)blockIdx.y * 64 + wave * 16;
  long row = m0 + l15;
  int k0 = bx * 512;
  float inv = 1.0f / load_scale(slot);

  const u16* hp = h + row * 4096 + k0 + quad * 8;
  const f16* ap = Ah + l15 * 4096 + k0 + quad * 8;
  f32x4 acc = {0.0f, 0.0f, 0.0f, 0.0f};
  u32 q[32];
#pragma unroll
  for (int s = 0; s < 16; s++) {
    uint4 hv = *(const uint4*)(hp + s * 32);   // 8 fp16 of h
    f16x8 af = *(const f16x8*)&hv;
    f16x8 bf = *(const f16x8*)(ap + s * 32);
    acc = __builtin_amdgcn_mfma_f32_16x16x32_f16(af, bf, acc, 0, 0, 0);
    u32 uu[4] = {hv.x, hv.y, hv.z, hv.w};
#pragma unroll
    for (int c = 0; c < 2; c++) {
      float2 f0 = __half22float2(*(__half2*)&uu[2 * c]);
      float2 f1 = __half22float2(*(__half2*)&uu[2 * c + 1]);
      q[2 * s + c] = ((u32)(quanti(f0.x, inv) & 255)) |
                     ((u32)(quanti(f0.y, inv) & 255) << 8) |
                     ((u32)(quanti(f1.x, inv) & 255) << 16) |
                     ((u32)(quanti(f1.y, inv) & 255) << 24);
    }
  }
  asm volatile("" ::: "memory");
  i8* op = (i8*)h + row * 8192 + bx * 1024 + quad * 8;
#pragma unroll
  for (int s = 0; s < 16; s++) {
    uint2 o = {q[2 * s], q[2 * s + 1]};
    *(uint2*)(op + s * 32) = o;
  }
  if (l15 < 8) {
#pragma unroll
    for (int r = 0; r < 4; r++) {
      long m = m0 + quad * 4 + r;
      atomicAdd(&t2[m * 8 + l15], acc[r]);
    }
  }
}

// ---------- reg-A pipelined i8 GEMM: C = Aq * Bq^T, BM=BN=128, BK=128 -------
// 256 threads, 4 waves (2Mx2N). A-frags load GLOBAL->VGPR directly (16
// K-contiguous bytes per lane; per (i,kk) a wave reads 16 rows x 64B — L2
// resident). Only B goes through LDS (dbuf 2x16KB, XOR-swizzled source,
// linear global_load_lds dest). Per K-tile t:
//   [issue A(t+1)->regs (8x dwordx4)] [ds_read b0,b1 (8x b128)]
//   [stageB(t+1) -> Bs[(t+1)&1] (4x ASYNC16)]
//   MFMA(a,b) x32 (compiler inserts counted lgkm waits for b-frags)
//   vmcnt(0)  [A(t+1) + B(t+1) landed; issued a full tile earlier]
//   SBAR      [all waves' b-reads of Bs[t&1] done -> next stage safe]
// Safety: stageB(t+1) writes Bs[(t+1)&1], whose readers finished in tile
// t-1 before that tile's trailing SBAR. A-regs double-buffered via
// unroll-2 (aP/aN named arrays, no runtime indexing).
// MODE 0: *scale+bias+2*t.Bl, GELU, fp16 h store, absmax(h).
// MODE 1: fp32 store; A in CHUNKED col layout (col c at byte
//         (c>>9)*1024+(c&511), rowstride 8192) -> koff(t) below.
template <int MODE>
__launch_bounds__(256, 2) __global__
    void gemmra_kernel(const i8* __restrict__ A, const i8* __restrict__ B,
                       int N, int K, int lda, int ldb,
                       const float* __restrict__ bias,
                       const float* __restrict__ tl,   // [M][8] f32
                       const float* __restrict__ Bl,   // [N][8] f32
                       const u32* __restrict__ scales, int sa, int sb,
                       void* __restrict__ outp, u32* __restrict__ hmax) {
  constexpr int MT = 4, NT = 4;
  __shared__ __align__(16) i8 Bs[2][128 * 128];
  __shared__ u32 bmax;
  int tid = threadIdx.x;
  int lane = tid & 63, wave = tid >> 6;
  int quad = lane >> 4, l15 = lane & 15;
  int wm = (wave & 1) * 64, wn = (wave >> 1) * 64;
  // XCD-bijective swizzle (nwg % 8 == 0 for both grids)
  int nwg = gridDim.x * gridDim.y;
  int lin = blockIdx.y * gridDim.x + blockIdx.x;
  int swb = (lin & 7) * (nwg >> 3) + (lin >> 3);
  int bx = swb % gridDim.x, by = swb / gridDim.x;
  long m0 = (long)by * 128;
  long n0 = (long)bx * 128;
  if (MODE == 0 && tid == 0) bmax = 0u;

  // B staging: 1024 chunks of 16B, 4/thread; row = c>>3, pre-swizzled src.
  const i8* pB[4];
  int ldsB[4];
#pragma unroll
  for (int u = 0; u < 4; u++) {
    int c = u * 256 + tid;
    int row = c >> 3;
    int swz = ((c & 7) ^ (row & 7)) * 16;
    pB[u] = B + (n0 + row) * ldb + swz;
    ldsB[u] = c * 16;
  }
  auto stageB = [&](int t) {
    int kb = t << 7;
#pragma unroll
    for (int u = 0; u < 4; u++) ASYNC16(pB[u] + kb, &Bs[t & 1][ldsB[u]]);
  };

  // A row bases: lane reads 16B at [wm+i*16+l15][koff + kk*64 + quad*16]
  const i8* rowA[MT];
#pragma unroll
  for (int i = 0; i < MT; i++)
    rowA[i] = A + (m0 + wm + i * 16 + l15) * (long)lda + quad * 16;
  auto koff = [&](int t) -> int {
    return (MODE == 1) ? ((t >> 2) * 1024 + (t & 3) * 128) : (t << 7);
  };
  auto loadA = [&](int t, i32x4 (&ar)[MT][2]) {
    int kb = koff(t);
#pragma unroll
    for (int i = 0; i < MT; i++) {
      ar[i][0] = *(const i32x4*)(rowA[i] + kb);
      ar[i][1] = *(const i32x4*)(rowA[i] + kb + 64);
    }
  };

  // b-frag swizzled chunk byte offsets: chunk = (kk*4+quad)^(l15&7)
  int s0 = (quad ^ (l15 & 7)) * 16;
  int s1 = s0 ^ 64;

  i32x4 acc[MT][NT] = {};
  int NTILES = K >> 7;  // 8 (gemm1) or 32 (gemm2) — always even

  auto body = [&](int t, i32x4 (&cur)[MT][2], i32x4 (&nxt)[MT][2]) {
    if (t + 1 < NTILES) loadA(t + 1, nxt);
    i32x4 b0[NT], b1[NT];
    const i8* Bb = Bs[t & 1];
#pragma unroll
    for (int j = 0; j < NT; j++) {
      b0[j] = *(const i32x4*)(Bb + (wn + j * 16 + l15) * 128 + s0);
      b1[j] = *(const i32x4*)(Bb + (wn + j * 16 + l15) * 128 + s1);
    }
    if (t + 1 < NTILES) stageB(t + 1);
    __builtin_amdgcn_s_setprio(1);
#pragma unroll
    for (int i = 0; i < MT; i++)
#pragma unroll
      for (int j = 0; j < NT; j++)
        acc[i][j] = __builtin_amdgcn_mfma_i32_16x16x64_i8(cur[i][0], b0[j],
                                                          acc[i][j], 0, 0, 0);
#pragma unroll
    for (int i = 0; i < MT; i++)
#pragma unroll
      for (int j = 0; j < NT; j++)
        acc[i][j] = __builtin_amdgcn_mfma_i32_16x16x64_i8(cur[i][1], b1[j],
                                                          acc[i][j], 0, 0, 0);
    __builtin_amdgcn_s_setprio(0);
    VMCNT0;   // A(t+1) regs + B(t+1) stage landed (issued a full tile ago)
    SBAR;     // all waves done reading Bs[t&1] -> next tile may stage into it
  };

  i32x4 aP[MT][2], aN[MT][2];
  loadA(0, aP);
  stageB(0);
  VMCNT0;
  SBAR;
  for (int t = 0; t < NTILES; t += 2) {
    body(t, aP, aN);
    body(t + 1, aN, aP);
  }

  // epilogue
  float scale = load_scale(scales + sa) * load_scale(scales + sb);
  float biasv[NT];
  float4 bl0[NT], bl1[NT];
#pragma unroll
  for (int j = 0; j < NT; j++) {
    long n = n0 + wn + j * 16 + l15;
    biasv[j] = bias[n];
    bl0[j] = ((const float4*)(Bl + n * 8))[0];
    bl1[j] = ((const float4*)(Bl + n * 8))[1];
  }
  float lmax = 0.0f;
#pragma unroll
  for (int i = 0; i < MT; i++) {
#pragma unroll
    for (int r = 0; r < 4; r++) {
      long m = m0 + wm + i * 16 + quad * 4 + r;
      float4 t0 = ((const float4*)(tl + m * 8))[0];
      float4 t1v = ((const float4*)(tl + m * 8))[1];
#pragma unroll
      for (int j = 0; j < NT; j++) {
        long n = n0 + wn + j * 16 + l15;
        float lora = t0.x * bl0[j].x + t0.y * bl0[j].y + t0.z * bl0[j].z +
                     t0.w * bl0[j].w + t1v.x * bl1[j].x + t1v.y * bl1[j].y +
                     t1v.z * bl1[j].z + t1v.w * bl1[j].w;
        float v = (float)acc[i][j][r] * scale + biasv[j] + 2.0f * lora;
        if (MODE == 0) {
          float hv = gelu_erf(v);
          __half hh = __float2half_rn(hv);
          ((u16*)outp)[m * N + n] = *(u16*)&hh;
          lmax = fmaxf(lmax, fabsf(hv));
        } else {
          ((float*)outp)[m * N + n] = v;
        }
      }
    }
  }
  if (MODE == 0) {
    atomicMax(&bmax, __float_as_uint(lmax));
    __syncthreads();
    if (tid == 0) atomicMax(hmax, bmax);
  }
}

extern "C" void kernel_launch(void* const* d_in, const int* in_sizes, int n_in,
                              void* d_out, int out_size, void* d_ws,
                              size_t ws_size, hipStream_t stream) {
  const float* x = (const float*)d_in[0];    // [8192][1024]
  const float* Wfc = (const float*)d_in[1];  // [4096][1024]
  const float* bfc = (const float*)d_in[2];  // [4096]
  const float* Afc = (const float*)d_in[3];  // [8][1024]
  const float* Bfc = (const float*)d_in[4];  // [4096][8]
  const float* Wpr = (const float*)d_in[5];  // [1024][4096]
  const float* bpr = (const float*)d_in[6];  // [1024]
  const float* Apr = (const float*)d_in[7];  // [8][4096]
  const float* Bpr = (const float*)d_in[8];  // [1024][8]
  float* out = (float*)d_out;                // fp32 [8192][1024]

  char* w = (char*)d_ws;
  u32* scales = (u32*)w;                   // 4 slots (fp32 bits): x, Wfc, Wpr, h
  float* t1 = (float*)(w + 256);           // [8192][8]
  float* t2 = (float*)(w + 256 + 262144);  // [8192][8]
  i8* xq = (i8*)(w + 524544);              // [8192][1024] i8
  f16* aprh = (f16*)(w + 8913152);         // [16][4096] fp16
  f16* afch = (f16*)(w + 9175040);         // [16][1024] fp16 (gap before wq1)
  i8* wq1 = (i8*)(w + 9437184);            // [4096][1024] i8
  i8* wq2 = (i8*)(w + 13631488);           // [1024][4096] i8
  u16* hq = (u16*)(w + 17825792);          // [8192][4096] fp16 h; i8 in place
  if (ws_size < 84934656) return;          // need ~81 MiB scratch

  hipMemsetAsync(w, 0, 524544, stream);    // scales + t1 + t2 (atomicAdd'd)
  conv_a16_kernel<<<32, 256, 0, stream>>>(Apr, aprh, 4096);
  conv_a16_kernel<<<8, 256, 0, stream>>>(Afc, afch, 1024);
  absmax_kernel<<<1024, 256, 0, stream>>>(x, 8192 * 1024 / 4, scales + 0);
  absmax_kernel<<<512, 256, 0, stream>>>(Wfc, 4096 * 1024 / 4, scales + 1);
  absmax_kernel<<<512, 256, 0, stream>>>(Wpr, 4096 * 1024 / 4, scales + 2);
  quant_x_t1_fused<<<dim3(2, 128), 256, 0, stream>>>(x, afch, scales + 0, xq,
                                                     t1);
  quant_w_kernel<<<256, 256, 0, stream>>>(Wfc, 4096 * 1024 / 16, scales + 1,
                                          wq1);
  quant_w_kernel<<<256, 256, 0, stream>>>(Wpr, 4096 * 1024 / 16, scales + 2,
                                          wq2);
  // gemm1: 8192x4096, K=1024, grid (32,64)=2048 (%8==0)
  gemmra_kernel<0><<<dim3(32, 64), 256, 0, stream>>>(
      xq, wq1, 4096, 1024, 1024, 1024, bfc, t1, Bfc, scales, 0, 1, hq,
      scales + 3);
  quant_h_t2_fused<<<dim3(8, 128), 256, 0, stream>>>(hq, aprh, scales + 3, t2);
  // gemm2: 8192x1024, K=4096, grid (8,64)=512 (%8==0)
  gemmra_kernel<1><<<dim3(8, 64), 256, 0, stream>>>(
      (const i8*)hq, wq2, 1024, 4096, 8192, 4096, bpr, t2, Bpr, scales, 3, 2,
      out, nullptr);
}